// Round 1
// 804.703 us; speedup vs baseline: 1.0387x; 1.0387x over previous
//
#include <hip/hip_runtime.h>

#define HW 4096
#define NC 512
#define NK 64
#define NB 64

typedef unsigned short u16;
typedef float  float4v __attribute__((ext_vector_type(4)));
typedef short  short8  __attribute__((ext_vector_type(8)));

__device__ __forceinline__ u16 f2bf(float f){
  unsigned u = __builtin_bit_cast(unsigned, f);
  u += 0x7fffu + ((u >> 16) & 1u);           // RNE to bf16
  return (u16)(u >> 16);
}
__device__ __forceinline__ unsigned pk2(float a, float b){
  return (unsigned)f2bf(a) | ((unsigned)f2bf(b) << 16);
}

// ---------------------------------------------------------------------------
// K1: per-pixel invnorm + 1x1-conv logits (bf16 MFMA) + softmax over K
// grid (16, 64): blockIdx.x = 256-pixel tile, blockIdx.y = batch. 256 thr.
// (unchanged this round)
// ---------------------------------------------------------------------------
__global__ __launch_bounds__(256) void nv_k1(
    const float* __restrict__ x, const float* __restrict__ w,
    const float* __restrict__ bias, float* __restrict__ invnorm,
    u16* __restrict__ a_out, float* __restrict__ asum)
{
  __shared__ u16 w_sh[NK * 40];     // [k][c_local] pitch 40 u16 (80 B)
  __shared__ u16 x_sh[256 * 40];    // [pixel][c_local] pitch 40 u16
  __shared__ float bias_sh[NK];

  const int t    = threadIdx.x;
  const int b    = blockIdx.y;
  const int p0   = blockIdx.x * 256;
  const int wave = t >> 6, lane = t & 63, q = lane >> 4, l16 = lane & 15;

  if (t < NK) bias_sh[t] = bias[t];

  const float* xb = x + (size_t)b * NC * HW;
  float sumsq = 0.f;

  float4v acc[4][4];
  const float4v zf = {0.f, 0.f, 0.f, 0.f};
  #pragma unroll
  for (int i = 0; i < 4; ++i)
    #pragma unroll
    for (int j = 0; j < 4; ++j) acc[i][j] = zf;

  for (int step = 0; step < 16; ++step){
    const int c0 = step * 32;
    __syncthreads();
    { // stage W chunk [64 x 32] -> bf16
      const int m = t >> 2, cq = (t & 3) * 8;
      const float* wp = w + m * NC + c0 + cq;
      float4 w0 = *(const float4*)wp;
      float4 w1 = *(const float4*)(wp + 4);
      uint4 pk;
      pk.x = pk2(w0.x, w0.y); pk.y = pk2(w0.z, w0.w);
      pk.z = pk2(w1.x, w1.y); pk.w = pk2(w1.z, w1.w);
      *(uint4*)&w_sh[m * 40 + cq] = pk;
    }
    { // stage X chunk [32 ch x 256 px] -> [px][ch] bf16, fused sumsq
      const float* xp = xb + (size_t)c0 * HW + p0 + t;
      #pragma unroll
      for (int c8 = 0; c8 < 4; ++c8){
        float v0 = xp[(c8*8+0)*HW], v1 = xp[(c8*8+1)*HW];
        float v2 = xp[(c8*8+2)*HW], v3 = xp[(c8*8+3)*HW];
        float v4 = xp[(c8*8+4)*HW], v5 = xp[(c8*8+5)*HW];
        float v6 = xp[(c8*8+6)*HW], v7 = xp[(c8*8+7)*HW];
        sumsq += v0*v0 + v1*v1 + v2*v2 + v3*v3 + v4*v4 + v5*v5 + v6*v6 + v7*v7;
        uint4 pk;
        pk.x = pk2(v0, v1); pk.y = pk2(v2, v3);
        pk.z = pk2(v4, v5); pk.w = pk2(v6, v7);
        *(uint4*)&x_sh[t * 40 + c8 * 8] = pk;
      }
    }
    __syncthreads();
    short8 av[4], bv[4];
    #pragma unroll
    for (int ms = 0; ms < 4; ++ms)
      av[ms] = *(const short8*)&w_sh[(ms*16 + l16) * 40 + q*8];
    #pragma unroll
    for (int ns = 0; ns < 4; ++ns)
      bv[ns] = *(const short8*)&x_sh[(wave*64 + ns*16 + l16) * 40 + q*8];
    #pragma unroll
    for (int ms = 0; ms < 4; ++ms)
      #pragma unroll
      for (int ns = 0; ns < 4; ++ns)
        acc[ms][ns] = __builtin_amdgcn_mfma_f32_16x16x32_bf16(av[ms], bv[ns], acc[ms][ns], 0, 0, 0);
  }

  // invnorm for this thread's pixel
  float inv = 1.f / fmaxf(sqrtf(sumsq), 1e-12f);
  invnorm[(size_t)b * HW + p0 + t] = inv;

  // softmax over K=64 (the 64 m-values for pixel n live in 4 q-lanes)
  float inv_n[4];
  #pragma unroll
  for (int ns = 0; ns < 4; ++ns) inv_n[ns] = __shfl(inv, ns*16 + l16, 64);

  #pragma unroll
  for (int ns = 0; ns < 4; ++ns){
    float mx = -3.4e38f;
    #pragma unroll
    for (int ms = 0; ms < 4; ++ms)
      #pragma unroll
      for (int r = 0; r < 4; ++r){
        float lv = fmaf(acc[ms][ns][r], inv_n[ns], bias_sh[ms*16 + q*4 + r]);
        acc[ms][ns][r] = lv;
        mx = fmaxf(mx, lv);
      }
    mx = fmaxf(mx, __shfl_xor(mx, 16, 64));
    mx = fmaxf(mx, __shfl_xor(mx, 32, 64));
    float s = 0.f;
    #pragma unroll
    for (int ms = 0; ms < 4; ++ms)
      #pragma unroll
      for (int r = 0; r < 4; ++r){
        float e = __expf(acc[ms][ns][r] - mx);
        acc[ms][ns][r] = e;
        s += e;
      }
    s += __shfl_xor(s, 16, 64);
    s += __shfl_xor(s, 32, 64);
    float is = 1.f / s;
    #pragma unroll
    for (int ms = 0; ms < 4; ++ms)
      #pragma unroll
      for (int r = 0; r < 4; ++r) acc[ms][ns][r] *= is;
  }

  // write soft-assign (bf16), coalesced in pixel dim
  u16* ap = a_out + (size_t)b * NK * HW + p0 + wave * 64;
  #pragma unroll
  for (int ms = 0; ms < 4; ++ms)
    #pragma unroll
    for (int r = 0; r < 4; ++r){
      const int m = ms*16 + q*4 + r;
      #pragma unroll
      for (int ns = 0; ns < 4; ++ns)
        ap[(size_t)m * HW + ns*16 + l16] = f2bf(acc[ms][ns][r]);
    }

  // asum[k] partials (fp32): sum over this wave's 64 pixels, then atomic
  #pragma unroll
  for (int ms = 0; ms < 4; ++ms)
    #pragma unroll
    for (int r = 0; r < 4; ++r){
      const int m = ms*16 + q*4 + r;
      float s = acc[ms][0][r] + acc[ms][1][r] + acc[ms][2][r] + acc[ms][3][r];
      s += __shfl_xor(s, 1, 64); s += __shfl_xor(s, 2, 64);
      s += __shfl_xor(s, 4, 64); s += __shfl_xor(s, 8, 64);
      if (l16 == 0) atomicAdd(&asum[b * NK + m], s);
    }
}

// ---------------------------------------------------------------------------
// K2: data term of vlad: part[iq][b,k,c] = sum_{i in quarter} a[k,i]*xf[i,c]
// Changes this round: invr[4][8] (32 VGPR of step-invariant data) moved to
// LDS (inv_sh, 8 KiB, conflict-free: 16 consecutive addrs x 4-way broadcast)
// + __launch_bounds__(256,3) to guarantee >=3 waves/SIMD for latency hiding
// of the 32 strided scalar x-loads per step.
// grid (2 c-tiles x 4 i-quarters x 64 b) = 512 blocks, 256 thr.
// ---------------------------------------------------------------------------
__global__ __launch_bounds__(256, 3) void nv_k2(
    const float* __restrict__ x, const u16* __restrict__ a_buf,
    const float* __restrict__ invnorm, float* __restrict__ vpart)
{
  __shared__ u16 a_sh[NK * 40];       // [k][i_local] pitch 40 u16
  __shared__ float inv_sh[8 * 256];   // [j][c_local]  (8 KiB)

  const int t    = threadIdx.x;
  const int b    = blockIdx.z;
  const int iq   = blockIdx.y;            // i in [iq*1024, iq*1024+1024)
  const int cc0  = blockIdx.x * 256;      // c-tile of 256
  const int wave = t >> 6, lane = t & 63, q = lane >> 4, l16 = lane & 15;

  const int cl = wave * 64 + l16;         // lane's base c_local (+ ns*16)

  // stage invnorm slice once: inv_sh[j][u] = invnorm[j*512 + cc0 + u]
  const float* invb = invnorm + (size_t)b * HW;
  #pragma unroll
  for (int j = 0; j < 8; ++j)
    inv_sh[j * 256 + t] = invb[j * 512 + cc0 + t];

  const float* xb  = x + (size_t)b * NC * HW;
  const u16*   ab  = a_buf + (size_t)b * NK * HW + iq * 1024;
  const float* xpb = xb + (size_t)(iq * 128 + q) * HW + cc0 + wave * 64 + l16;

  float4v acc[4][4];
  const float4v zf = {0.f, 0.f, 0.f, 0.f};
  #pragma unroll
  for (int i = 0; i < 4; ++i)
    #pragma unroll
    for (int j = 0; j < 4; ++j) acc[i][j] = zf;

  for (int step = 0; step < 32; ++step){
    const int i0 = step * 32;
    __syncthreads();                      // also covers inv_sh writes (iter 0)
    { // stage a tile [64 k x 32 i] (bf16, natural layout)
      const int k = t >> 2, i8 = (t & 3) * 8;
      *(float4*)&a_sh[k * 40 + i8] = *(const float4*)&ab[(size_t)k * HW + i0 + i8];
    }
    __syncthreads();
    short8 av[4];
    #pragma unroll
    for (int ms = 0; ms < 4; ++ms)
      av[ms] = *(const short8*)&a_sh[(ms*16 + l16) * 40 + q*8];

    const float* xs = xpb + (size_t)step * 4 * HW;   // ch advances 4 per step
    #pragma unroll
    for (int ns = 0; ns < 4; ++ns){
      float v[8];
      #pragma unroll
      for (int j = 0; j < 8; ++j)
        v[j] = xs[j * 512 + ns * 16] * inv_sh[j * 256 + cl + ns * 16];
      short8 bv;
      #pragma unroll
      for (int j = 0; j < 4; ++j)
        ((unsigned*)&bv)[j] = pk2(v[2*j], v[2*j+1]);
      #pragma unroll
      for (int ms = 0; ms < 4; ++ms)
        acc[ms][ns] = __builtin_amdgcn_mfma_f32_16x16x32_bf16(av[ms], bv, acc[ms][ns], 0, 0, 0);
    }
  }

  float* vp = vpart + (size_t)(iq * NB + b) * NK * NC;
  #pragma unroll
  for (int ms = 0; ms < 4; ++ms)
    #pragma unroll
    for (int ns = 0; ns < 4; ++ns)
      #pragma unroll
      for (int r = 0; r < 4; ++r){
        const int m = ms*16 + q*4 + r;
        const int n = cc0 + wave*64 + ns*16 + l16;
        vp[(size_t)m * NC + n] = acc[ms][ns][r];
      }
}

// ---------------------------------------------------------------------------
// K3a: vlad = sum_iq part[iq] - asum*cent; per-(b,k) row sumsq -> rstat.
// Changes: grid 64 -> 256 blocks (4 k-groups x 64 b) for full-chip coverage.
// 16 threads per k-row, lane-contiguous float4 loads (256 B / 16-lane group).
// rstat[b][0..63]=rinv, [64..127]=s_k
// ---------------------------------------------------------------------------
__global__ __launch_bounds__(256) void nv_k3a(
    const float* __restrict__ vpart, const float* __restrict__ asum,
    const float* __restrict__ cent, float* __restrict__ vlad,
    float* __restrict__ rstat)
{
  const int b = blockIdx.y, kg = blockIdx.x, t = threadIdx.x;
  const int k = kg * 16 + (t >> 4), seg = t & 15;
  const size_t roff = ((size_t)b * NK + k) * NC + seg * 4;
  const size_t bstride = (size_t)NB * NK * NC;
  const float* p0 = vpart + roff;
  const float as = asum[b * NK + k];
  const float* cp = cent + (size_t)k * NC + seg * 4;
  float* vp = vlad + roff;

  float s = 0.f;
  #pragma unroll
  for (int j = 0; j < 8; ++j){
    const int o = j * 64;                 // lanes interleave: coalesced 256 B
    float4 a0 = *(const float4*)&p0[o];
    float4 a1 = *(const float4*)&p0[bstride + o];
    float4 a2 = *(const float4*)&p0[2*bstride + o];
    float4 a3 = *(const float4*)&p0[3*bstride + o];
    float4 c4 = *(const float4*)&cp[o];
    float4 v;
    v.x = (a0.x + a1.x) + (a2.x + a3.x) - as * c4.x;
    v.y = (a0.y + a1.y) + (a2.y + a3.y) - as * c4.y;
    v.z = (a0.z + a1.z) + (a2.z + a3.z) - as * c4.z;
    v.w = (a0.w + a1.w) + (a2.w + a3.w) - as * c4.w;
    *(float4*)&vp[o] = v;
    s += v.x*v.x + v.y*v.y + v.z*v.z + v.w*v.w;
  }
  // reduce across the 16 lanes of this k-row
  s += __shfl_xor(s, 1, 64); s += __shfl_xor(s, 2, 64);
  s += __shfl_xor(s, 4, 64); s += __shfl_xor(s, 8, 64);
  if (seg == 0){
    float ri = 1.f / fmaxf(sqrtf(s), 1e-12f);
    rstat[b * 128 + k]      = ri;
    rstat[b * 128 + 64 + k] = s * ri * ri;  // sumsq of normalized row
  }
}

// ---------------------------------------------------------------------------
// K3c: out = vlad * rinv[k] * gscale(b).
// Changes: grid 64 -> 256 blocks (4 c-quarters x 64 b); each block redundantly
// reduces the 64 per-row sumsqs for its batch (cheap: 64 floats from L2).
// ---------------------------------------------------------------------------
__global__ __launch_bounds__(256) void nv_k3c(
    const float* __restrict__ vlad, const float* __restrict__ rstat,
    float* __restrict__ out)
{
  __shared__ float rinv_sh[16];
  __shared__ float gsh;
  const int b = blockIdx.y, qg = blockIdx.x, t = threadIdx.x;
  if (t < 64){  // wave 0: global scale
    float sk = rstat[b * 128 + 64 + t];
    sk += __shfl_xor(sk, 1, 64);  sk += __shfl_xor(sk, 2, 64);
    sk += __shfl_xor(sk, 4, 64);  sk += __shfl_xor(sk, 8, 64);
    sk += __shfl_xor(sk, 16, 64); sk += __shfl_xor(sk, 32, 64);
    if (t == 0) gsh = 1.f / fmaxf(sqrtf(sk), 1e-12f);
  } else if (t < 80){
    rinv_sh[t - 64] = rstat[b * 128 + qg * 16 + (t - 64)];
  }
  __syncthreads();
  const float g = gsh;
  const float* vb = vlad + (size_t)b * NK * NC + qg * 8192;
  float* ob = out + (size_t)b * NK * NC + qg * 8192;
  #pragma unroll
  for (int j = 0; j < 8; ++j){
    const int idx = j * 1024 + t * 4;
    float4 v = *(const float4*)&vb[idx];
    float sc = rinv_sh[idx >> 9] * g;
    float4 o; o.x = v.x*sc; o.y = v.y*sc; o.z = v.z*sc; o.w = v.w*sc;
    *(float4*)&ob[idx] = o;
  }
}

// ---------------------------------------------------------------------------
extern "C" void kernel_launch(void* const* d_in, const int* in_sizes, int n_in,
                              void* d_out, int out_size, void* d_ws, size_t ws_size,
                              hipStream_t stream)
{
  (void)in_sizes; (void)n_in; (void)out_size; (void)ws_size;
  const float* x    = (const float*)d_in[0];
  const float* w    = (const float*)d_in[1];
  const float* bias = (const float*)d_in[2];
  const float* cent = (const float*)d_in[3];
  float* out = (float*)d_out;

  char* ws = (char*)d_ws;
  float* invnorm = (float*)ws;                              // 1 MiB
  u16*   a_buf   = (u16*)(ws + (1u  << 20));                // 32 MiB
  float* asum    = (float*)(ws + (33u << 20));              // 16 KiB
  float* rstat   = (float*)(ws + (33u << 20) + 65536u);     // 32 KiB
  float* vlad    = (float*)(ws + (34u << 20));              // 8 MiB
  float* vpart   = (float*)(ws + (42u << 20));              // 32 MiB

  hipMemsetAsync(asum, 0, NB * NK * sizeof(float), stream);
  hipLaunchKernelGGL(nv_k1, dim3(16, 64), dim3(256), 0, stream,
                     x, w, bias, invnorm, a_buf, asum);
  hipLaunchKernelGGL(nv_k2, dim3(2, 4, 64), dim3(256), 0, stream,
                     x, a_buf, invnorm, vpart);
  hipLaunchKernelGGL(nv_k3a, dim3(4, 64), dim3(256), 0, stream,
                     vpart, asum, cent, vlad, rstat);
  hipLaunchKernelGGL(nv_k3c, dim3(4, 64), dim3(256), 0, stream,
                     vlad, rstat, out);
}